// Round 12
// baseline (118.351 us; speedup 1.0000x reference)
//
#include <hip/hip_runtime.h>

// Problem constants: B=2, L=16, N=10000, FIN=8, H=64, P=12, E=80000, K=3
#define NN   10000
#define LL   16
#define FINC 8
#define HH   64
#define PP   12
#define EE   80000
#define BLH  256   // (b,lp,h) = 2*2*64 — only l=14,15 feed out[:,:,-1] (K=3, pad=1)
#define CAP  64    // per-row edge bucket capacity; E/N = 8, P(deg>64) ~ 0

// ---------------------------------------------------------------------------
// k1 v3: 2500 blocks x 256 threads, 4 nodes per block (fully unrolled).
// W_in held in 8 registers; x read via wave-uniform scalar loads; no LDS,
// no sync. Blocks 0..39 zero deg.
// ---------------------------------------------------------------------------
__global__ __launch_bounds__(256) void k1_input_proj(
        const float* __restrict__ x, const float* __restrict__ W_in,
        const float* __restrict__ b_in, float* __restrict__ hsmall,
        int* __restrict__ deg) {
    const int t  = threadIdx.x;
    const int bl = __builtin_amdgcn_readfirstlane(t >> 6);  // wave-uniform (b*2+lp)
    const int h  = t & 63;
    const int b  = bl >> 1, lp = bl & 1;

    if (blockIdx.x < 40) {                 // zero deg (10000 ints over 40 blocks)
        int di = blockIdx.x * 256 + t;
        if (di < NN) deg[di] = 0;
    }

    float w[FINC];
#pragma unroll
    for (int f = 0; f < FINC; ++f) w[f] = W_in[f * HH + h];   // coalesced, L2-hot
    const float bias = b_in[h];
    const float* xb = x + (size_t)(b * LL + 14 + lp) * NN * FINC;
    const int g = blockIdx.x * 4;

#pragma unroll
    for (int nn = 0; nn < 4; ++nn) {
        const int n = g + nn;
        float4 xa = *(const float4*)&xb[(size_t)n * 8];       // uniform -> s_load
        float4 xc = *(const float4*)&xb[(size_t)n * 8 + 4];
        float acc = bias;
        acc = fmaf(xa.x, w[0], acc); acc = fmaf(xa.y, w[1], acc);
        acc = fmaf(xa.z, w[2], acc); acc = fmaf(xa.w, w[3], acc);
        acc = fmaf(xc.x, w[4], acc); acc = fmaf(xc.y, w[5], acc);
        acc = fmaf(xc.z, w[6], acc); acc = fmaf(xc.w, w[7], acc);
        hsmall[(size_t)n * BLH + t] = fmaxf(acc, 0.f);
    }
}

// ---------------------------------------------------------------------------
// k2: bucketed CSR build + pack W_tcn taps {0,1} into Wt[k][o] (k = lp*64+i).
// ---------------------------------------------------------------------------
__global__ __launch_bounds__(256) void k2_build(
        const int* __restrict__ row, const int* __restrict__ col,
        const float* __restrict__ vals, int* __restrict__ deg,
        int2* __restrict__ bucket, const float* __restrict__ W_tcn,
        float* __restrict__ Wt) {
    int e = blockIdx.x * 256 + threadIdx.x;
    if (e < EE) {
        int r = row[e];
        int pos = atomicAdd(&deg[r], 1);
        if (pos < CAP)
            bucket[(size_t)r * CAP + pos] = make_int2(col[e], __float_as_int(vals[e]));
    } else if (e < EE + 3 * HH * HH) {
        int f = e - EE;                 // linear index into W_tcn [o][i][k3]
        int kk = f % 3;
        if (kk < 2) {
            int o = f / (HH * 3);
            int i = (f / 3) % HH;
            Wt[(kk * HH + i) * HH + o] = W_tcn[f];
        }
    }
}

// ---------------------------------------------------------------------------
// k3: gather-aggregate, zero LDS. One wave per node; metadata via one
// coalesced 512B load + shfl broadcast (entries >= deg masked to {0, 0.0});
// 8 independent row loads in flight.
// ---------------------------------------------------------------------------
__global__ __launch_bounds__(256) void k3_gather(
        const float* __restrict__ hsmall, const int* __restrict__ deg,
        const int2* __restrict__ bucket, float* __restrict__ h2) {
    const int wave = threadIdx.x >> 6;
    const int lane = threadIdx.x & 63;
    const int n = blockIdx.x * 4 + wave;
    const int dn  = min(deg[n], CAP);
    const int dnp = (dn + 7) & ~7;
    const int2 meta = bucket[(size_t)n * CAP + lane];   // poison beyond dn — masked

    float4 acc = make_float4(0.f, 0.f, 0.f, 0.f);
    for (int i = 0; i < dnp; i += 8) {
        int   c[8];
        float v[8];
#pragma unroll
        for (int j = 0; j < 8; ++j) {
            int idx = i + j;
            int   cc = __shfl(meta.x, idx);
            float vv = __int_as_float(__shfl(meta.y, idx));
            bool ok = idx < dn;
            c[j] = ok ? cc : 0;
            v[j] = ok ? vv : 0.f;
        }
        float4 hv[8];
#pragma unroll
        for (int j = 0; j < 8; ++j)
            hv[j] = *(const float4*)&hsmall[(size_t)c[j] * BLH + lane * 4];
#pragma unroll
        for (int j = 0; j < 8; ++j) {
            acc.x = fmaf(v[j], hv[j].x, acc.x);
            acc.y = fmaf(v[j], hv[j].y, acc.y);
            acc.z = fmaf(v[j], hv[j].z, acc.z);
            acc.w = fmaf(v[j], hv[j].w, acc.w);
        }
    }
    float4 r = make_float4(fmaxf(acc.x, 0.f), fmaxf(acc.y, 0.f),
                           fmaxf(acc.z, 0.f), fmaxf(acc.w, 0.f));
    *(float4*)&h2[(size_t)n * BLH + lane * 4] = r;
}

// ---------------------------------------------------------------------------
// k4 v7: role swap.  lane = o; Wt half in 64 VGPRs loaded ONCE per wave
// (coalesced, L2-hot); s = h2 row values are wave-uniform -> s_load_dwordx4
// straight from global (NO s_tile staging, NO pre-K barrier).  8 waves x
// 8 rows = 64 rows (32 nodes) per block.  Rows processed in pairs for ILP.
// acc = pre-activation (row, o=lane) -> relu+bias -> hl[row][o] in LDS
// (16.6 KB, conflict-free) -> one barrier -> wave 0 epilogue (lane = row,
// 16 ds_read_b128 at structural minimum, W_out via hot s_loads).
// ---------------------------------------------------------------------------
__global__ __launch_bounds__(512) void k4_head(
        const float* __restrict__ h2, const float* __restrict__ Wt,
        const float* __restrict__ b_tcn, const float* __restrict__ W_out,
        const float* __restrict__ b_out, float* __restrict__ y) {
    __shared__ float hl[64 * 65];      // 16.6 KB
    const int t    = threadIdx.x;      // 0..511
    const int lane = t & 63;           // = o in phase 1, = row in epilogue
    const int w    = __builtin_amdgcn_readfirstlane(t >> 6);  // wave id 0..7
    const int n0   = blockIdx.x * 32;
    const float bias = b_tcn[lane];

    float accs[8];
#pragma unroll
    for (int r = 0; r < 8; ++r) accs[r] = 0.f;

    // grow = global row index (2*n + b); this wave's rows: grow0 .. grow0+7
    const size_t grow0 = (size_t)2 * n0 + w * 8;

#pragma unroll
    for (int half = 0; half < 2; ++half) {
        // Wt half -> VGPRs, once per wave: wreg[kk] = Wt[half*64+kk][lane]
        float wreg[64];
#pragma unroll
        for (int kk = 0; kk < 64; ++kk)
            wreg[kk] = Wt[(half * 64 + kk) * HH + lane];   // coalesced 256B/load
        // rows in pairs: two independent acc chains hide s_load + FMA latency
#pragma unroll
        for (int pr = 0; pr < 4; ++pr) {
            const float4* sA = (const float4*)(h2 + (grow0 + pr * 2) * 128 + half * 64);
            const float4* sB = (const float4*)(h2 + (grow0 + pr * 2 + 1) * 128 + half * 64);
            float a0 = accs[pr * 2], a1 = accs[pr * 2 + 1];
#pragma unroll
            for (int q = 0; q < 16; ++q) {
                float4 va = sA[q];     // wave-uniform -> s_load_dwordx4
                float4 vb = sB[q];
                a0 = fmaf(wreg[4 * q + 0], va.x, a0);
                a1 = fmaf(wreg[4 * q + 0], vb.x, a1);
                a0 = fmaf(wreg[4 * q + 1], va.y, a0);
                a1 = fmaf(wreg[4 * q + 1], vb.y, a1);
                a0 = fmaf(wreg[4 * q + 2], va.z, a0);
                a1 = fmaf(wreg[4 * q + 2], vb.z, a1);
                a0 = fmaf(wreg[4 * q + 3], va.w, a0);
                a1 = fmaf(wreg[4 * q + 3], vb.w, a1);
            }
            accs[pr * 2] = a0; accs[pr * 2 + 1] = a1;
        }
    }
    // relu + bias -> hl[row][o]; banks (row+lane)%32, 2 lanes/bank = free
#pragma unroll
    for (int r = 0; r < 8; ++r)
        hl[(w * 8 + r) * 65 + lane] = fmaxf(accs[r] + bias, 0.f);
    __syncthreads();

    // epilogue: wave 0 only; lane = row (row = nn*2+b)
    if (w == 0) {
        float out[PP];
#pragma unroll
        for (int p = 0; p < PP; ++p) out[p] = b_out[p];
#pragma unroll
        for (int j = 0; j < 16; ++j) {
            float4 h4 = *(const float4*)&hl[lane * 65 + 4 * j];  // structural-min b128
            float hv[4] = {h4.x, h4.y, h4.z, h4.w};
#pragma unroll
            for (int i = 0; i < 4; ++i) {
                const int o = 4 * j + i;
#pragma unroll
                for (int p = 0; p < PP; ++p)
                    out[p] = fmaf(hv[i], W_out[o * PP + p], out[p]);  // hot s_loads
            }
        }
        const int n = n0 + (lane >> 1), b = lane & 1;
        if (n < NN) {
#pragma unroll
            for (int p = 0; p < PP; ++p)
                y[((size_t)(b * PP + p)) * NN + n] = out[p];
        }
    }
}

// ---------------------------------------------------------------------------
extern "C" void kernel_launch(void* const* d_in, const int* in_sizes, int n_in,
                              void* d_out, int out_size, void* d_ws, size_t ws_size,
                              hipStream_t stream) {
    const float* x     = (const float*)d_in[0];
    const int*   row   = (const int*)d_in[1];
    const int*   col   = (const int*)d_in[2];
    const float* vals  = (const float*)d_in[3];
    const float* W_in  = (const float*)d_in[4];
    const float* b_in  = (const float*)d_in[5];
    const float* W_tcn = (const float*)d_in[6];
    const float* b_tcn = (const float*)d_in[7];
    const float* W_out = (const float*)d_in[8];
    const float* b_out = (const float*)d_in[9];
    float* y = (float*)d_out;

    char* ws = (char*)d_ws;
    float* hsmall = (float*)(ws);                    // 10,240,000 B
    int*   deg    = (int*)(ws + 10240000);           //     40,000 B
    int2*  bucket = (int2*)(ws + 10280000);          //  5,120,000 B
    float* h2     = (float*)(ws + 15400000);         // 10,240,000 B
    float* Wt     = (float*)(ws + 25640000);         //     32,768 B
    // note: k4's last block reads ~16KB past h2 (nodes 10000..10015) — lands
    // in the allocated Wt region; garbage values are masked by the n<NN guard.

    k1_input_proj<<<NN / 4, 256, 0, stream>>>(x, W_in, b_in, hsmall, deg);
    k2_build<<<(EE + 3 * HH * HH + 255) / 256, 256, 0, stream>>>(
        row, col, vals, deg, bucket, W_tcn, Wt);
    k3_gather<<<NN / 4, 256, 0, stream>>>(hsmall, deg, bucket, h2);
    // 32 nodes (64 rows) per block, 512 threads (8 waves x 8 rows) -> 313 blocks
    k4_head<<<(NN + 31) / 32, 512, 0, stream>>>(h2, Wt, b_tcn, W_out, b_out, y);
}

// Round 13
// 112.662 us; speedup vs baseline: 1.0505x; 1.0505x over previous
//
#include <hip/hip_runtime.h>

// Problem constants: B=2, L=16, N=10000, FIN=8, H=64, P=12, E=80000, K=3
#define NN   10000
#define LL   16
#define FINC 8
#define HH   64
#define PP   12
#define EE   80000
#define BLH  256   // (b,lp,h) = 2*2*64 — only l=14,15 feed out[:,:,-1] (K=3, pad=1)
#define CAP  64    // per-row edge bucket capacity; E/N = 8, P(deg>64) ~ 0
#define RS   132   // k4 row stride (pad 128+4): 16B-aligned

// ---------------------------------------------------------------------------
// k1 v4: blocks 0..2499 = input projection (4 nodes each, unrolled, scalar x
// loads, W_in in registers); blocks 0..39 also zero deg; blocks 2500..2547
// pack W_tcn taps {0,1} into Wt[k][o] (independent of edges -> moved out of k2).
// ---------------------------------------------------------------------------
__global__ __launch_bounds__(256) void k1_input_proj(
        const float* __restrict__ x, const float* __restrict__ W_in,
        const float* __restrict__ b_in, const float* __restrict__ W_tcn,
        float* __restrict__ hsmall, int* __restrict__ deg,
        float* __restrict__ Wt) {
    const int t = threadIdx.x;
    if (blockIdx.x >= NN / 4) {            // Wt-pack tail blocks
        int f = (blockIdx.x - NN / 4) * 256 + t;   // f < 3*64*64 = 12288 exactly
        int kk = f % 3;
        if (kk < 2) {
            int o = f / (HH * 3);
            int i = (f / 3) % HH;
            Wt[(kk * HH + i) * HH + o] = W_tcn[f];
        }
        return;
    }
    const int bl = __builtin_amdgcn_readfirstlane(t >> 6);  // wave-uniform (b*2+lp)
    const int h  = t & 63;
    const int b  = bl >> 1, lp = bl & 1;

    if (blockIdx.x < 40) {                 // zero deg (10000 ints over 40 blocks)
        int di = blockIdx.x * 256 + t;
        if (di < NN) deg[di] = 0;
    }

    float w[FINC];
#pragma unroll
    for (int f = 0; f < FINC; ++f) w[f] = W_in[f * HH + h];   // coalesced, L2-hot
    const float bias = b_in[h];
    const float* xb = x + (size_t)(b * LL + 14 + lp) * NN * FINC;
    const int g = blockIdx.x * 4;

#pragma unroll
    for (int nn = 0; nn < 4; ++nn) {
        const int n = g + nn;
        float4 xa = *(const float4*)&xb[(size_t)n * 8];       // uniform -> s_load
        float4 xc = *(const float4*)&xb[(size_t)n * 8 + 4];
        float acc = bias;
        acc = fmaf(xa.x, w[0], acc); acc = fmaf(xa.y, w[1], acc);
        acc = fmaf(xa.z, w[2], acc); acc = fmaf(xa.w, w[3], acc);
        acc = fmaf(xc.x, w[4], acc); acc = fmaf(xc.y, w[5], acc);
        acc = fmaf(xc.z, w[6], acc); acc = fmaf(xc.w, w[7], acc);
        hsmall[(size_t)n * BLH + t] = fmaxf(acc, 0.f);
    }
}

// ---------------------------------------------------------------------------
// k2: pure bucketed CSR build (Wt-pack moved to k1).
// ---------------------------------------------------------------------------
__global__ __launch_bounds__(256) void k2_build(
        const int* __restrict__ row, const int* __restrict__ col,
        const float* __restrict__ vals, int* __restrict__ deg,
        int2* __restrict__ bucket) {
    int e = blockIdx.x * 256 + threadIdx.x;
    if (e < EE) {
        int r = row[e];
        int pos = atomicAdd(&deg[r], 1);
        if (pos < CAP)
            bucket[(size_t)r * CAP + pos] = make_int2(col[e], __float_as_int(vals[e]));
    }
}

// ---------------------------------------------------------------------------
// k3 v2: gather-aggregate, 2 nodes per wave — 16 row-loads in flight (vs 8)
// to A/B-test latency-bound vs L3-BW-bound.  Batch guards (doA/doB) are
// wave-uniform (deg of the wave's own nodes) — no divergence.  Zero LDS.
// ---------------------------------------------------------------------------
__global__ __launch_bounds__(256, 4) void k3_gather(
        const float* __restrict__ hsmall, const int* __restrict__ deg,
        const int2* __restrict__ bucket, float* __restrict__ h2) {
    const int wave = threadIdx.x >> 6;
    const int lane = threadIdx.x & 63;
    const int nA = (blockIdx.x * 4 + wave) * 2;   // nodes nA, nA+1 (max 9999)
    const int nB = nA + 1;
    const int dnA = min(deg[nA], CAP), dnB = min(deg[nB], CAP);
    const int2 metaA = bucket[(size_t)nA * CAP + lane];   // poison beyond dn — masked
    const int2 metaB = bucket[(size_t)nB * CAP + lane];
    const int dnpA = (dnA + 7) & ~7, dnpB = (dnB + 7) & ~7;
    const int mx = max(dnpA, dnpB);

    float4 accA = make_float4(0.f, 0.f, 0.f, 0.f);
    float4 accB = make_float4(0.f, 0.f, 0.f, 0.f);
    for (int i = 0; i < mx; i += 8) {
        const bool doA = i < dnpA, doB = i < dnpB;   // wave-uniform branches
        int   cA[8], cB[8];
        float vA[8], vB[8];
#pragma unroll
        for (int j = 0; j < 8; ++j) {
            int idx = i + j;
            int   ca = __shfl(metaA.x, idx);
            float va = __int_as_float(__shfl(metaA.y, idx));
            int   cb = __shfl(metaB.x, idx);
            float vb = __int_as_float(__shfl(metaB.y, idx));
            cA[j] = (idx < dnA) ? ca : 0;  vA[j] = (idx < dnA) ? va : 0.f;
            cB[j] = (idx < dnB) ? cb : 0;  vB[j] = (idx < dnB) ? vb : 0.f;
        }
        float4 hA[8], hB[8];
        if (doA) {
#pragma unroll
            for (int j = 0; j < 8; ++j)
                hA[j] = *(const float4*)&hsmall[(size_t)cA[j] * BLH + lane * 4];
        }
        if (doB) {
#pragma unroll
            for (int j = 0; j < 8; ++j)
                hB[j] = *(const float4*)&hsmall[(size_t)cB[j] * BLH + lane * 4];
        }
        if (doA) {
#pragma unroll
            for (int j = 0; j < 8; ++j) {
                accA.x = fmaf(vA[j], hA[j].x, accA.x);
                accA.y = fmaf(vA[j], hA[j].y, accA.y);
                accA.z = fmaf(vA[j], hA[j].z, accA.z);
                accA.w = fmaf(vA[j], hA[j].w, accA.w);
            }
        }
        if (doB) {
#pragma unroll
            for (int j = 0; j < 8; ++j) {
                accB.x = fmaf(vB[j], hB[j].x, accB.x);
                accB.y = fmaf(vB[j], hB[j].y, accB.y);
                accB.z = fmaf(vB[j], hB[j].z, accB.z);
                accB.w = fmaf(vB[j], hB[j].w, accB.w);
            }
        }
    }
    float4 rA = make_float4(fmaxf(accA.x, 0.f), fmaxf(accA.y, 0.f),
                            fmaxf(accA.z, 0.f), fmaxf(accA.w, 0.f));
    float4 rB = make_float4(fmaxf(accB.x, 0.f), fmaxf(accB.y, 0.f),
                            fmaxf(accB.z, 0.f), fmaxf(accB.w, 0.f));
    *(float4*)&h2[(size_t)nA * BLH + lane * 4] = rA;
    *(float4*)&h2[(size_t)nB * BLH + lane * 4] = rB;
}

// ---------------------------------------------------------------------------
// k4 v5 (r11 known-best, 13 us): split-K x2, acc[8], 1024 threads.
// 1024 threads = 64 rows x 8 o-groups x 2 K-halves; 4 k per ds_read_b128
// (32 FMA per LDS read); Wt via wave-uniform s_loads; stride-9 reduction.
// ---------------------------------------------------------------------------
__global__ __launch_bounds__(1024, 8) void k4_head(
        const float* __restrict__ h2, const float* __restrict__ Wt,
        const float* __restrict__ b_tcn, const float* __restrict__ W_out,
        const float* __restrict__ b_out, float* __restrict__ y) {
    __shared__ float pool[64 * RS];    // 33.8 KB: s_tile[row][k], then hl[o*65+row]
    __shared__ float red[512 * 9];     // 18.4 KB: kq=1 partials, stride-9
    __shared__ float Wo[HH * PP];      // 3 KB
    const int t   = threadIdx.x;       // 0..1023
    const int row = t & 63;
    const int og  = __builtin_amdgcn_readfirstlane((t >> 6) & 7);  // wave-uniform
    const int kq  = __builtin_amdgcn_readfirstlane(t >> 9);        // wave-uniform
    const int n0  = blockIdx.x * 32;

    for (int idx = t; idx < HH * PP; idx += 1024) Wo[idx] = W_out[idx];
    const float4* h2v = (const float4*)h2;
    for (int idx4 = t; idx4 < 32 * (BLH / 4); idx4 += 1024) {
        int nn = idx4 >> 6, q = idx4 & 63;       // b=q>>5, k0=(q&31)*4
        int r  = nn * 2 + (q >> 5);
        int k0 = (q & 31) * 4;
        float4 v = make_float4(0.f, 0.f, 0.f, 0.f);
        if (n0 + nn < NN) v = h2v[(size_t)(n0 + nn) * (BLH / 4) + q];
        *(float4*)&pool[r * RS + k0] = v;        // aligned b128 write
    }
    __syncthreads();

    const float4* Wt4 = (const float4*)Wt;    // Wt[k*64+o] -> float4 idx k*16+o/4
    float acc[8];
#pragma unroll
    for (int j = 0; j < 8; ++j) acc[j] = 0.f;

    const int kbase = kq * 64;
#pragma unroll 4
    for (int kk = 0; kk < 16; ++kk) {
        const int k0 = kbase + kk * 4;
        float4 s4 = *(const float4*)&pool[row * RS + k0];   // 1 ds_read_b128 = 4 k
        float sv[4] = {s4.x, s4.y, s4.z, s4.w};
#pragma unroll
        for (int j = 0; j < 4; ++j) {
            const int k = k0 + j;
            float4 w0 = Wt4[k * 16 + og * 2 + 0];   // wave-uniform -> s_load
            float4 w1 = Wt4[k * 16 + og * 2 + 1];
            float v = sv[j];
            acc[0] = fmaf(v, w0.x, acc[0]); acc[1] = fmaf(v, w0.y, acc[1]);
            acc[2] = fmaf(v, w0.z, acc[2]); acc[3] = fmaf(v, w0.w, acc[3]);
            acc[4] = fmaf(v, w1.x, acc[4]); acc[5] = fmaf(v, w1.y, acc[5]);
            acc[6] = fmaf(v, w1.z, acc[6]); acc[7] = fmaf(v, w1.w, acc[7]);
        }
    }
    if (kq == 1) {
#pragma unroll
        for (int j = 0; j < 8; ++j) red[(t - 512) * 9 + j] = acc[j];
    }
    __syncthreads();   // also: all s_tile reads done; pool reusable

    if (kq == 0) {
        const float4* bt4 = (const float4*)b_tcn;   // wave-uniform scalar loads
        float4 b0 = bt4[og * 2 + 0], b1 = bt4[og * 2 + 1];
        float bt[8] = {b0.x, b0.y, b0.z, b0.w, b1.x, b1.y, b1.z, b1.w};
#pragma unroll
        for (int j = 0; j < 8; ++j) {
            float s2 = acc[j] + red[t * 9 + j];
            pool[(og * 8 + j) * 65 + row] = fmaxf(s2 + bt[j], 0.f);  // hl[o][row]
        }
    }
    __syncthreads();

    // epilogue: 768 outputs = 64 rows (n,b encoded) x 12 p
    if (t < 64 * PP) {
        int r2 = t & 63, p = t >> 6;           // p in 0..11
        int n = n0 + (r2 >> 1), b = r2 & 1;
        float yy = b_out[p];
#pragma unroll 8
        for (int o = 0; o < HH; ++o)
            yy = fmaf(pool[o * 65 + r2], Wo[o * PP + p], yy);
        if (n < NN) y[((size_t)(b * PP + p)) * NN + n] = yy;
    }
}

// ---------------------------------------------------------------------------
extern "C" void kernel_launch(void* const* d_in, const int* in_sizes, int n_in,
                              void* d_out, int out_size, void* d_ws, size_t ws_size,
                              hipStream_t stream) {
    const float* x     = (const float*)d_in[0];
    const int*   row   = (const int*)d_in[1];
    const int*   col   = (const int*)d_in[2];
    const float* vals  = (const float*)d_in[3];
    const float* W_in  = (const float*)d_in[4];
    const float* b_in  = (const float*)d_in[5];
    const float* W_tcn = (const float*)d_in[6];
    const float* b_tcn = (const float*)d_in[7];
    const float* W_out = (const float*)d_in[8];
    const float* b_out = (const float*)d_in[9];
    float* y = (float*)d_out;

    char* ws = (char*)d_ws;
    float* hsmall = (float*)(ws);                    // 10,240,000 B
    int*   deg    = (int*)(ws + 10240000);           //     40,000 B
    int2*  bucket = (int2*)(ws + 10280000);          //  5,120,000 B
    float* h2     = (float*)(ws + 15400000);         // 10,240,000 B
    float* Wt     = (float*)(ws + 25640000);         //     32,768 B

    // 2500 projection blocks + 48 Wt-pack blocks
    k1_input_proj<<<NN / 4 + 48, 256, 0, stream>>>(x, W_in, b_in, W_tcn,
                                                   hsmall, deg, Wt);
    k2_build<<<(EE + 255) / 256, 256, 0, stream>>>(row, col, vals, deg, bucket);
    // 2 nodes per wave, 4 waves per block -> 1250 blocks
    k3_gather<<<NN / 8, 256, 0, stream>>>(hsmall, deg, bucket, h2);
    // 32 nodes (64 rows) per block, 1024 threads (8 og x 2 kq) -> 313 blocks
    k4_head<<<(NN + 31) / 32, 1024, 0, stream>>>(h2, Wt, b_tcn, W_out, b_out, y);
}

// Round 14
// 106.870 us; speedup vs baseline: 1.1074x; 1.0542x over previous
//
#include <hip/hip_runtime.h>
#include <hip/hip_fp16.h>

// Problem constants: B=2, L=16, N=10000, FIN=8, H=64, P=12, E=80000, K=3
#define NN   10000
#define LL   16
#define FINC 8
#define HH   64
#define PP   12
#define EE   80000
#define BLH  256   // (b,lp,h) = 2*2*64 — only l=14,15 feed out[:,:,-1] (K=3, pad=1)
#define CAP  64    // per-row edge bucket capacity; E/N = 8, P(deg>64) ~ 0
#define RS   132   // k4 row stride (pad 128+4): 16B-aligned

// ---------------------------------------------------------------------------
// k1 v3h: 2500 blocks x 256 threads, 4 nodes per block (fully unrolled).
// W_in in registers; x via wave-uniform scalar loads; OUTPUT IN FP16
// (halves k3's L3-BW-bound gather traffic).  Blocks 0..39 zero deg.
// ---------------------------------------------------------------------------
__global__ __launch_bounds__(256) void k1_input_proj(
        const float* __restrict__ x, const float* __restrict__ W_in,
        const float* __restrict__ b_in, __half* __restrict__ hsmall,
        int* __restrict__ deg) {
    const int t  = threadIdx.x;
    const int bl = __builtin_amdgcn_readfirstlane(t >> 6);  // wave-uniform (b*2+lp)
    const int h  = t & 63;
    const int b  = bl >> 1, lp = bl & 1;

    if (blockIdx.x < 40) {                 // zero deg (10000 ints over 40 blocks)
        int di = blockIdx.x * 256 + t;
        if (di < NN) deg[di] = 0;
    }

    float w[FINC];
#pragma unroll
    for (int f = 0; f < FINC; ++f) w[f] = W_in[f * HH + h];   // coalesced, L2-hot
    const float bias = b_in[h];
    const float* xb = x + (size_t)(b * LL + 14 + lp) * NN * FINC;
    const int g = blockIdx.x * 4;

#pragma unroll
    for (int nn = 0; nn < 4; ++nn) {
        const int n = g + nn;
        float4 xa = *(const float4*)&xb[(size_t)n * 8];       // uniform -> s_load
        float4 xc = *(const float4*)&xb[(size_t)n * 8 + 4];
        float acc = bias;
        acc = fmaf(xa.x, w[0], acc); acc = fmaf(xa.y, w[1], acc);
        acc = fmaf(xa.z, w[2], acc); acc = fmaf(xa.w, w[3], acc);
        acc = fmaf(xc.x, w[4], acc); acc = fmaf(xc.y, w[5], acc);
        acc = fmaf(xc.z, w[6], acc); acc = fmaf(xc.w, w[7], acc);
        hsmall[(size_t)n * BLH + t] = __float2half_rn(fmaxf(acc, 0.f));
    }
}

// ---------------------------------------------------------------------------
// k2: bucketed CSR build + pack W_tcn taps {0,1} into Wt[k][o] (k = lp*64+i).
// ---------------------------------------------------------------------------
__global__ __launch_bounds__(256) void k2_build(
        const int* __restrict__ row, const int* __restrict__ col,
        const float* __restrict__ vals, int* __restrict__ deg,
        int2* __restrict__ bucket, const float* __restrict__ W_tcn,
        float* __restrict__ Wt) {
    int e = blockIdx.x * 256 + threadIdx.x;
    if (e < EE) {
        int r = row[e];
        int pos = atomicAdd(&deg[r], 1);
        if (pos < CAP)
            bucket[(size_t)r * CAP + pos] = make_int2(col[e], __float_as_int(vals[e]));
    } else if (e < EE + 3 * HH * HH) {
        int f = e - EE;                 // linear index into W_tcn [o][i][k3]
        int kk = f % 3;
        if (kk < 2) {
            int o = f / (HH * 3);
            int i = (f / 3) % HH;
            Wt[(kk * HH + i) * HH + o] = W_tcn[f];
        }
    }
}

// ---------------------------------------------------------------------------
// k3 v3h: gather-aggregate over FP16 rows (512B/row, 8B/lane) — half the
// L3-BW-bound traffic of r11.  One wave per node; metadata via one coalesced
// 512B load + shfl broadcast (masked beyond deg); 8 row-loads in flight;
// unpack half2->float2 at consume time; accumulate and write h2 in FP32.
// ---------------------------------------------------------------------------
__global__ __launch_bounds__(256) void k3_gather(
        const __half* __restrict__ hsmall, const int* __restrict__ deg,
        const int2* __restrict__ bucket, float* __restrict__ h2) {
    const int wave = threadIdx.x >> 6;
    const int lane = threadIdx.x & 63;
    const int n = blockIdx.x * 4 + wave;
    const int dn  = min(deg[n], CAP);
    const int dnp = (dn + 7) & ~7;
    const int2 meta = bucket[(size_t)n * CAP + lane];   // poison beyond dn — masked

    float4 acc = make_float4(0.f, 0.f, 0.f, 0.f);
    for (int i = 0; i < dnp; i += 8) {
        int   c[8];
        float v[8];
#pragma unroll
        for (int j = 0; j < 8; ++j) {
            int idx = i + j;
            int   cc = __shfl(meta.x, idx);
            float vv = __int_as_float(__shfl(meta.y, idx));
            bool ok = idx < dn;
            c[j] = ok ? cc : 0;
            v[j] = ok ? vv : 0.f;
        }
        uint2 hv[8];
#pragma unroll
        for (int j = 0; j < 8; ++j)
            hv[j] = *(const uint2*)((const char*)hsmall +
                                    ((size_t)c[j] * BLH + lane * 4) * 2);
#pragma unroll
        for (int j = 0; j < 8; ++j) {
            float2 f0 = __half22float2(*(const __half2*)&hv[j].x);
            float2 f1 = __half22float2(*(const __half2*)&hv[j].y);
            acc.x = fmaf(v[j], f0.x, acc.x);
            acc.y = fmaf(v[j], f0.y, acc.y);
            acc.z = fmaf(v[j], f1.x, acc.z);
            acc.w = fmaf(v[j], f1.y, acc.w);
        }
    }
    float4 r = make_float4(fmaxf(acc.x, 0.f), fmaxf(acc.y, 0.f),
                           fmaxf(acc.z, 0.f), fmaxf(acc.w, 0.f));
    *(float4*)&h2[(size_t)n * BLH + lane * 4] = r;
}

// ---------------------------------------------------------------------------
// k4 v5 (r11 known-best, 13 us): split-K x2, acc[8], 1024 threads.
// 1024 threads = 64 rows x 8 o-groups x 2 K-halves; 4 k per ds_read_b128
// (32 FMA per LDS read); Wt via wave-uniform s_loads; stride-9 reduction.
// ---------------------------------------------------------------------------
__global__ __launch_bounds__(1024, 8) void k4_head(
        const float* __restrict__ h2, const float* __restrict__ Wt,
        const float* __restrict__ b_tcn, const float* __restrict__ W_out,
        const float* __restrict__ b_out, float* __restrict__ y) {
    __shared__ float pool[64 * RS];    // 33.8 KB: s_tile[row][k], then hl[o*65+row]
    __shared__ float red[512 * 9];     // 18.4 KB: kq=1 partials, stride-9
    __shared__ float Wo[HH * PP];      // 3 KB
    const int t   = threadIdx.x;       // 0..1023
    const int row = t & 63;
    const int og  = __builtin_amdgcn_readfirstlane((t >> 6) & 7);  // wave-uniform
    const int kq  = __builtin_amdgcn_readfirstlane(t >> 9);        // wave-uniform
    const int n0  = blockIdx.x * 32;

    for (int idx = t; idx < HH * PP; idx += 1024) Wo[idx] = W_out[idx];
    const float4* h2v = (const float4*)h2;
    for (int idx4 = t; idx4 < 32 * (BLH / 4); idx4 += 1024) {
        int nn = idx4 >> 6, q = idx4 & 63;       // b=q>>5, k0=(q&31)*4
        int r  = nn * 2 + (q >> 5);
        int k0 = (q & 31) * 4;
        float4 v = make_float4(0.f, 0.f, 0.f, 0.f);
        if (n0 + nn < NN) v = h2v[(size_t)(n0 + nn) * (BLH / 4) + q];
        *(float4*)&pool[r * RS + k0] = v;        // aligned b128 write
    }
    __syncthreads();

    const float4* Wt4 = (const float4*)Wt;    // Wt[k*64+o] -> float4 idx k*16+o/4
    float acc[8];
#pragma unroll
    for (int j = 0; j < 8; ++j) acc[j] = 0.f;

    const int kbase = kq * 64;
#pragma unroll 4
    for (int kk = 0; kk < 16; ++kk) {
        const int k0 = kbase + kk * 4;
        float4 s4 = *(const float4*)&pool[row * RS + k0];   // 1 ds_read_b128 = 4 k
        float sv[4] = {s4.x, s4.y, s4.z, s4.w};
#pragma unroll
        for (int j = 0; j < 4; ++j) {
            const int k = k0 + j;
            float4 w0 = Wt4[k * 16 + og * 2 + 0];   // wave-uniform -> s_load
            float4 w1 = Wt4[k * 16 + og * 2 + 1];
            float v = sv[j];
            acc[0] = fmaf(v, w0.x, acc[0]); acc[1] = fmaf(v, w0.y, acc[1]);
            acc[2] = fmaf(v, w0.z, acc[2]); acc[3] = fmaf(v, w0.w, acc[3]);
            acc[4] = fmaf(v, w1.x, acc[4]); acc[5] = fmaf(v, w1.y, acc[5]);
            acc[6] = fmaf(v, w1.z, acc[6]); acc[7] = fmaf(v, w1.w, acc[7]);
        }
    }
    if (kq == 1) {
#pragma unroll
        for (int j = 0; j < 8; ++j) red[(t - 512) * 9 + j] = acc[j];
    }
    __syncthreads();   // also: all s_tile reads done; pool reusable

    if (kq == 0) {
        const float4* bt4 = (const float4*)b_tcn;   // wave-uniform scalar loads
        float4 b0 = bt4[og * 2 + 0], b1 = bt4[og * 2 + 1];
        float bt[8] = {b0.x, b0.y, b0.z, b0.w, b1.x, b1.y, b1.z, b1.w};
#pragma unroll
        for (int j = 0; j < 8; ++j) {
            float s2 = acc[j] + red[t * 9 + j];
            pool[(og * 8 + j) * 65 + row] = fmaxf(s2 + bt[j], 0.f);  // hl[o][row]
        }
    }
    __syncthreads();

    // epilogue: 768 outputs = 64 rows (n,b encoded) x 12 p
    if (t < 64 * PP) {
        int r2 = t & 63, p = t >> 6;           // p in 0..11
        int n = n0 + (r2 >> 1), b = r2 & 1;
        float yy = b_out[p];
#pragma unroll 8
        for (int o = 0; o < HH; ++o)
            yy = fmaf(pool[o * 65 + r2], Wo[o * PP + p], yy);
        if (n < NN) y[((size_t)(b * PP + p)) * NN + n] = yy;
    }
}

// ---------------------------------------------------------------------------
extern "C" void kernel_launch(void* const* d_in, const int* in_sizes, int n_in,
                              void* d_out, int out_size, void* d_ws, size_t ws_size,
                              hipStream_t stream) {
    const float* x     = (const float*)d_in[0];
    const int*   row   = (const int*)d_in[1];
    const int*   col   = (const int*)d_in[2];
    const float* vals  = (const float*)d_in[3];
    const float* W_in  = (const float*)d_in[4];
    const float* b_in  = (const float*)d_in[5];
    const float* W_tcn = (const float*)d_in[6];
    const float* b_tcn = (const float*)d_in[7];
    const float* W_out = (const float*)d_in[8];
    const float* b_out = (const float*)d_in[9];
    float* y = (float*)d_out;

    char* ws = (char*)d_ws;
    __half* hsmall = (__half*)(ws);                  //  5,120,000 B (fp16 now)
    int*    deg    = (int*)(ws + 5120000);           //     40,000 B
    int2*   bucket = (int2*)(ws + 5160000);          //  5,120,000 B
    float*  h2     = (float*)(ws + 10280000);        // 10,240,000 B
    float*  Wt     = (float*)(ws + 20520000);        //     32,768 B

    k1_input_proj<<<NN / 4, 256, 0, stream>>>(x, W_in, b_in, hsmall, deg);
    k2_build<<<(EE + 3 * HH * HH + 255) / 256, 256, 0, stream>>>(
        row, col, vals, deg, bucket, W_tcn, Wt);
    k3_gather<<<NN / 4, 256, 0, stream>>>(hsmall, deg, bucket, h2);
    // 32 nodes (64 rows) per block, 1024 threads (8 og x 2 kq) -> 313 blocks
    k4_head<<<(NN + 31) / 32, 1024, 0, stream>>>(h2, Wt, b_tcn, W_out, b_out, y);
}

// Round 15
// 103.386 us; speedup vs baseline: 1.1448x; 1.0337x over previous
//
#include <hip/hip_runtime.h>
#include <hip/hip_fp16.h>

// Problem constants: B=2, L=16, N=10000, FIN=8, H=64, P=12, E=80000, K=3
#define NN   10000
#define LL   16
#define FINC 8
#define HH   64
#define PP   12
#define EE   80000
#define BLH  256   // (b,lp,h) = 2*2*64 — only l=14,15 feed out[:,:,-1] (K=3, pad=1)
#define CAP  64    // per-row edge bucket capacity; E/N = 8, P(deg>64) ~ 0
#define RS   132   // fused-tile row stride (pad 128+4): 16B-aligned

// ---------------------------------------------------------------------------
// k1 v3h: 2500 blocks x 256 threads, 4 nodes per block (fully unrolled).
// W_in in registers; x via wave-uniform scalar loads; OUTPUT IN FP16
// (halves the L3-BW-bound gather traffic).  Blocks 0..39 zero deg.
// ---------------------------------------------------------------------------
__global__ __launch_bounds__(256) void k1_input_proj(
        const float* __restrict__ x, const float* __restrict__ W_in,
        const float* __restrict__ b_in, __half* __restrict__ hsmall,
        int* __restrict__ deg) {
    const int t  = threadIdx.x;
    const int bl = __builtin_amdgcn_readfirstlane(t >> 6);  // wave-uniform (b*2+lp)
    const int h  = t & 63;
    const int b  = bl >> 1, lp = bl & 1;

    if (blockIdx.x < 40) {                 // zero deg (10000 ints over 40 blocks)
        int di = blockIdx.x * 256 + t;
        if (di < NN) deg[di] = 0;
    }

    float w[FINC];
#pragma unroll
    for (int f = 0; f < FINC; ++f) w[f] = W_in[f * HH + h];   // coalesced, L2-hot
    const float bias = b_in[h];
    const float* xb = x + (size_t)(b * LL + 14 + lp) * NN * FINC;
    const int g = blockIdx.x * 4;

#pragma unroll
    for (int nn = 0; nn < 4; ++nn) {
        const int n = g + nn;
        float4 xa = *(const float4*)&xb[(size_t)n * 8];       // uniform -> s_load
        float4 xc = *(const float4*)&xb[(size_t)n * 8 + 4];
        float acc = bias;
        acc = fmaf(xa.x, w[0], acc); acc = fmaf(xa.y, w[1], acc);
        acc = fmaf(xa.z, w[2], acc); acc = fmaf(xa.w, w[3], acc);
        acc = fmaf(xc.x, w[4], acc); acc = fmaf(xc.y, w[5], acc);
        acc = fmaf(xc.z, w[6], acc); acc = fmaf(xc.w, w[7], acc);
        hsmall[(size_t)n * BLH + t] = __float2half_rn(fmaxf(acc, 0.f));
    }
}

// ---------------------------------------------------------------------------
// k2: bucketed CSR build + pack W_tcn taps {0,1} into Wt[k][o] (k = lp*64+i).
// ---------------------------------------------------------------------------
__global__ __launch_bounds__(256) void k2_build(
        const int* __restrict__ row, const int* __restrict__ col,
        const float* __restrict__ vals, int* __restrict__ deg,
        int2* __restrict__ bucket, const float* __restrict__ W_tcn,
        float* __restrict__ Wt) {
    int e = blockIdx.x * 256 + threadIdx.x;
    if (e < EE) {
        int r = row[e];
        int pos = atomicAdd(&deg[r], 1);
        if (pos < CAP)
            bucket[(size_t)r * CAP + pos] = make_int2(col[e], __float_as_int(vals[e]));
    } else if (e < EE + 3 * HH * HH) {
        int f = e - EE;                 // linear index into W_tcn [o][i][k3]
        int kk = f % 3;
        if (kk < 2) {
            int o = f / (HH * 3);
            int i = (f / 3) % HH;
            Wt[(kk * HH + i) * HH + o] = W_tcn[f];
        }
    }
}

// ---------------------------------------------------------------------------
// k34 fused: gather-aggregate (fp16 rows) -> LDS tile -> head GEMM -> y.
// Kills the 20 MB h2 round-trip + one dispatch.
// Phase 1: 16 waves x 2 nodes = 32 nodes/block; wave gathers a node's edges
//   (one coalesced 512B metadata load + shfl broadcast, 8 row-loads in
//   flight, masked beyond deg), ReLUs, writes float4 DIRECTLY into
//   pool[row][k] (row=2nn+b, k=lp*64+h — same layout k4 staged from h2).
// Phase 2: r11's k4 v5 verbatim: 1024 thr = 64 rows x 8 og x 2 kq; 4 k per
//   ds_read_b128 (32 FMA/LDS-read); Wt via wave-uniform s_loads; stride-9
//   LDS reduction; pool reused as hl[o*65+row]; 768-output epilogue.
// ---------------------------------------------------------------------------
__global__ __launch_bounds__(1024, 8) void k34_fused(
        const __half* __restrict__ hsmall, const int* __restrict__ deg,
        const int2* __restrict__ bucket, const float* __restrict__ Wt,
        const float* __restrict__ b_tcn, const float* __restrict__ W_out,
        const float* __restrict__ b_out, float* __restrict__ y) {
    __shared__ float pool[64 * RS];    // 33.8 KB: gathered tile, then hl
    __shared__ float red[512 * 9];     // 18.4 KB: kq=1 partials, stride-9
    __shared__ float Wo[HH * PP];      // 3 KB
    const int t    = threadIdx.x;      // 0..1023
    const int lane = t & 63;
    const int w    = __builtin_amdgcn_readfirstlane(t >> 6);  // wave 0..15
    const int n0   = blockIdx.x * 32;

    for (int idx = t; idx < HH * PP; idx += 1024) Wo[idx] = W_out[idx];

    // ---- phase 1: gather 2 nodes per wave, write tile directly ----
#pragma unroll
    for (int i = 0; i < 2; ++i) {
        const int nn = 2 * w + i;              // 0..31
        const int n  = n0 + nn;                // wave-uniform
        float4 acc = make_float4(0.f, 0.f, 0.f, 0.f);
        if (n < NN) {
            const int dn  = min(deg[n], CAP);
            const int dnp = (dn + 7) & ~7;
            const int2 meta = bucket[(size_t)n * CAP + lane];  // masked beyond dn
            for (int e0 = 0; e0 < dnp; e0 += 8) {
                int   c[8];
                float v[8];
#pragma unroll
                for (int j = 0; j < 8; ++j) {
                    int idx = e0 + j;
                    int   cc = __shfl(meta.x, idx);
                    float vv = __int_as_float(__shfl(meta.y, idx));
                    bool ok = idx < dn;
                    c[j] = ok ? cc : 0;
                    v[j] = ok ? vv : 0.f;
                }
                uint2 hv[8];
#pragma unroll
                for (int j = 0; j < 8; ++j)
                    hv[j] = *(const uint2*)((const char*)hsmall +
                                            ((size_t)c[j] * BLH + lane * 4) * 2);
#pragma unroll
                for (int j = 0; j < 8; ++j) {
                    float2 f0 = __half22float2(*(const __half2*)&hv[j].x);
                    float2 f1 = __half22float2(*(const __half2*)&hv[j].y);
                    acc.x = fmaf(v[j], f0.x, acc.x);
                    acc.y = fmaf(v[j], f0.y, acc.y);
                    acc.z = fmaf(v[j], f1.x, acc.z);
                    acc.w = fmaf(v[j], f1.y, acc.w);
                }
            }
        }
        // ReLU -> pool[row][k]; j0=4*lane; row=2nn+(j0>>7); k=j0&127
        const int j0  = 4 * lane;
        const int row = nn * 2 + (j0 >> 7);
        const int k   = j0 & 127;
        float4 r = make_float4(fmaxf(acc.x, 0.f), fmaxf(acc.y, 0.f),
                               fmaxf(acc.z, 0.f), fmaxf(acc.w, 0.f));
        *(float4*)&pool[row * RS + k] = r;     // aligned b128 write
    }
    __syncthreads();

    // ---- phase 2: head GEMM (r11 k4 v5 verbatim) ----
    const int row = t & 63;
    const int og  = __builtin_amdgcn_readfirstlane((t >> 6) & 7);
    const int kq  = __builtin_amdgcn_readfirstlane(t >> 9);

    const float4* Wt4 = (const float4*)Wt;    // Wt[k*64+o] -> float4 idx k*16+o/4
    float acc[8];
#pragma unroll
    for (int j = 0; j < 8; ++j) acc[j] = 0.f;

    const int kbase = kq * 64;
#pragma unroll 4
    for (int kk = 0; kk < 16; ++kk) {
        const int k0 = kbase + kk * 4;
        float4 s4 = *(const float4*)&pool[row * RS + k0];   // 1 ds_read_b128 = 4 k
        float sv[4] = {s4.x, s4.y, s4.z, s4.w};
#pragma unroll
        for (int j = 0; j < 4; ++j) {
            const int k = k0 + j;
            float4 w0 = Wt4[k * 16 + og * 2 + 0];   // wave-uniform -> s_load
            float4 w1 = Wt4[k * 16 + og * 2 + 1];
            float v = sv[j];
            acc[0] = fmaf(v, w0.x, acc[0]); acc[1] = fmaf(v, w0.y, acc[1]);
            acc[2] = fmaf(v, w0.z, acc[2]); acc[3] = fmaf(v, w0.w, acc[3]);
            acc[4] = fmaf(v, w1.x, acc[4]); acc[5] = fmaf(v, w1.y, acc[5]);
            acc[6] = fmaf(v, w1.z, acc[6]); acc[7] = fmaf(v, w1.w, acc[7]);
        }
    }
    if (kq == 1) {
#pragma unroll
        for (int j = 0; j < 8; ++j) red[(t - 512) * 9 + j] = acc[j];
    }
    __syncthreads();   // all tile reads done; pool reusable as hl

    if (kq == 0) {
        const float4* bt4 = (const float4*)b_tcn;   // wave-uniform scalar loads
        float4 b0 = bt4[og * 2 + 0], b1 = bt4[og * 2 + 1];
        float bt[8] = {b0.x, b0.y, b0.z, b0.w, b1.x, b1.y, b1.z, b1.w};
#pragma unroll
        for (int j = 0; j < 8; ++j) {
            float s2 = acc[j] + red[t * 9 + j];
            pool[(og * 8 + j) * 65 + row] = fmaxf(s2 + bt[j], 0.f);  // hl[o][row]
        }
    }
    __syncthreads();

    // epilogue: 768 outputs = 64 rows (n,b encoded) x 12 p
    if (t < 64 * PP) {
        int r2 = t & 63, p = t >> 6;           // p in 0..11
        int n = n0 + (r2 >> 1), b = r2 & 1;
        float yy = b_out[p];
#pragma unroll 8
        for (int o = 0; o < HH; ++o)
            yy = fmaf(pool[o * 65 + r2], Wo[o * PP + p], yy);
        if (n < NN) y[((size_t)(b * PP + p)) * NN + n] = yy;
    }
}

// ---------------------------------------------------------------------------
extern "C" void kernel_launch(void* const* d_in, const int* in_sizes, int n_in,
                              void* d_out, int out_size, void* d_ws, size_t ws_size,
                              hipStream_t stream) {
    const float* x     = (const float*)d_in[0];
    const int*   row   = (const int*)d_in[1];
    const int*   col   = (const int*)d_in[2];
    const float* vals  = (const float*)d_in[3];
    const float* W_in  = (const float*)d_in[4];
    const float* b_in  = (const float*)d_in[5];
    const float* W_tcn = (const float*)d_in[6];
    const float* b_tcn = (const float*)d_in[7];
    const float* W_out = (const float*)d_in[8];
    const float* b_out = (const float*)d_in[9];
    float* y = (float*)d_out;

    char* ws = (char*)d_ws;
    __half* hsmall = (__half*)(ws);                  //  5,120,000 B (fp16)
    int*    deg    = (int*)(ws + 5120000);           //     40,000 B
    int2*   bucket = (int2*)(ws + 5160000);          //  5,120,000 B
    float*  Wt     = (float*)(ws + 10280000);        //     32,768 B

    k1_input_proj<<<NN / 4, 256, 0, stream>>>(x, W_in, b_in, hsmall, deg);
    k2_build<<<(EE + 3 * HH * HH + 255) / 256, 256, 0, stream>>>(
        row, col, vals, deg, bucket, W_tcn, Wt);
    // 32 nodes per block (16 waves x 2 nodes) -> 313 blocks
    k34_fused<<<(NN + 31) / 32, 1024, 0, stream>>>(hsmall, deg, bucket, Wt,
                                                   b_tcn, W_out, b_out, y);
}